// Round 1
// 481.380 us; speedup vs baseline: 1.0508x; 1.0508x over previous
//
#include <hip/hip_runtime.h>
#include <math.h>

// SCSA: x(32,512,64,64) fp32 -> 256 "images" of 64ch x 64 x 64 (G=8).
//   ch 0-31 : channel attention  x * sigmoid(cw*gap + cb)        -> k_chan
//   ch 32-63: spatial attention  x * sigmoid(a_h[h]*a_w[w]*x_s)  -> k_final
// Output channel shuffle: cc (concat order) -> cf = 2*(cc&255) + (cc>>8).
//
// Kernel order is chosen for Infinity-Cache residency: x1 (134 MB < 256 MiB
// LLC) is read LAST before k_final re-reads it. Never-reused streams (x0
// loads, all out stores) use non-temporal hints so they don't evict x1.

#define HW 4096      // 64*64
#define CG 32        // channels per half-group
#define NBG 256      // 32 batches * 8 groups

typedef float f32x4 __attribute__((ext_vector_type(4)));

__device__ __forceinline__ float sigmoidf_(float t) {
    return 1.0f / (1.0f + __expf(-t));
}

// ---------------------------------------------------------------------------
// Kernel 1: channel-attention half. One block per x0 plane (8192 blocks x 256).
// Only the plane's global mean is needed -> no row/col machinery, ~32 VGPRs,
// plane held in 4 float4/thread between reduce and scaled store.
// ---------------------------------------------------------------------------
__global__ __launch_bounds__(256) void k_chan(
    const float* __restrict__ x,
    const float* __restrict__ cweight, const float* __restrict__ cbias,
    float* __restrict__ out) {
    int p  = blockIdx.x;            // 0..8191
    int bg = p >> 5, c = p & 31;    // image, channel
    int n  = bg >> 3, g = bg & 7;
    const f32x4* src = (const f32x4*)(x + (size_t)(n * 512 + g * 64 + c) * HW);
    int cc = g * 64 + c;
    int cf = 2 * (cc & 255) + (cc >> 8);
    f32x4* dst = (f32x4*)(out + (size_t)(n * 512 + cf) * HW);
    int t = threadIdx.x;

    f32x4 v[4];
    float s = 0.f;
#pragma unroll
    for (int q = 0; q < 4; ++q) {
        v[q] = __builtin_nontemporal_load(&src[q * 256 + t]);
        s += (v[q][0] + v[q][1]) + (v[q][2] + v[q][3]);
    }
    // block-wide sum: wave shuffle tree, then 4 partials through LDS
    s += __shfl_xor(s, 1);  s += __shfl_xor(s, 2);  s += __shfl_xor(s, 4);
    s += __shfl_xor(s, 8);  s += __shfl_xor(s, 16); s += __shfl_xor(s, 32);
    __shared__ float wpart[4];
    if ((t & 63) == 0) wpart[t >> 6] = s;
    __syncthreads();
    float tot = (wpart[0] + wpart[1]) + (wpart[2] + wpart[3]);
    float sc = sigmoidf_(cweight[c] * (tot * (1.0f / HW)) + cbias[c]);
#pragma unroll
    for (int q = 0; q < 4; ++q) {
        f32x4 w = v[q] * sc;
        __builtin_nontemporal_store(w, &dst[q * 256 + t]);
    }
}

// ---------------------------------------------------------------------------
// Kernel 2: x1 pooled features. One block per x1 plane (8192 blocks x 256).
// Writes x_s (global mean), x_h (row means), x_w (col means). Read-only on x1
// with normal (caching) loads -> x1 is the freshest 134 MB in the LLC.
// Thread t, iter q covers float4 vi=q*256+t: row = q*16+(t>>4), cols (t&15)*4..+3.
// ---------------------------------------------------------------------------
__global__ __launch_bounds__(256) void k_pool(
    const float* __restrict__ x,
    float* __restrict__ x_s, float* __restrict__ x_h, float* __restrict__ x_w) {
    int p  = blockIdx.x;
    int bg = p >> 5, c = p & 31;
    int n  = bg >> 3, g = bg & 7;
    const f32x4* src = (const f32x4*)(x + (size_t)(n * 512 + g * 64 + 32 + c) * HW);
    int t = threadIdx.x;
    int l = t & 63, wid = t >> 6;

    __shared__ float rowsum[64];
    __shared__ __align__(16) float colpart[4][64];
    __shared__ float totpart[4];

    float cx0 = 0.f, cx1 = 0.f, cx2 = 0.f, cx3 = 0.f;
    float s = 0.f;
    float rs[4];
#pragma unroll
    for (int q = 0; q < 4; ++q) {
        f32x4 v = src[q * 256 + t];
        float r4 = (v[0] + v[1]) + (v[2] + v[3]);
        rs[q] = r4; s += r4;
        cx0 += v[0]; cx1 += v[1]; cx2 += v[2]; cx3 += v[3];
    }
    // row sums: 16 consecutive lanes share a row
#pragma unroll
    for (int q = 0; q < 4; ++q) {
        float r = rs[q];
        r += __shfl_xor(r, 1); r += __shfl_xor(r, 2);
        r += __shfl_xor(r, 4); r += __shfl_xor(r, 8);
        if ((l & 15) == 0) rowsum[q * 16 + (t >> 4)] = r;
    }
    // col partial sums: lanes {l, l^16, l^32, l^48} share the same 4 columns
    cx0 += __shfl_xor(cx0, 16); cx0 += __shfl_xor(cx0, 32);
    cx1 += __shfl_xor(cx1, 16); cx1 += __shfl_xor(cx1, 32);
    cx2 += __shfl_xor(cx2, 16); cx2 += __shfl_xor(cx2, 32);
    cx3 += __shfl_xor(cx3, 16); cx3 += __shfl_xor(cx3, 32);
    if (l < 16) {
        f32x4 cw = {cx0, cx1, cx2, cx3};
        ((f32x4*)&colpart[wid][0])[l] = cw;
    }
    // total
    s += __shfl_xor(s, 1);  s += __shfl_xor(s, 2);  s += __shfl_xor(s, 4);
    s += __shfl_xor(s, 8);  s += __shfl_xor(s, 16); s += __shfl_xor(s, 32);
    if (l == 0) totpart[wid] = s;
    __syncthreads();
    if (t < 64) {
        float cs = (colpart[0][t] + colpart[1][t]) + (colpart[2][t] + colpart[3][t]);
        x_w[(size_t)(bg * CG + c) * 64 + t] = cs * (1.0f / 64.0f);
        x_h[(size_t)(bg * CG + c) * 64 + t] = rowsum[t] * (1.0f / 64.0f);
        if (t == 0) {
            float tot = (totpart[0] + totpart[1]) + (totpart[2] + totpart[3]);
            x_s[bg * CG + c] = tot * (1.0f / HW);
        }
    }
}

// ---------------------------------------------------------------------------
// Kernel 3: per-image conv1 -> GN -> h-swish -> convh/convw. 256 blocks x 128.
// Weights staged in LDS once (3 x 4 KB) -> inner loops are same-address
// LDS broadcasts (conflict-free) instead of per-FMA global loads.
// ---------------------------------------------------------------------------
__global__ __launch_bounds__(128) void k_mid(
    const float* __restrict__ x_h, const float* __restrict__ x_w,
    const float* __restrict__ x_s,
    const float* __restrict__ w1, const float* __restrict__ b1,
    const float* __restrict__ gn_g, const float* __restrict__ gn_b,
    const float* __restrict__ wh, const float* __restrict__ bh,
    const float* __restrict__ ww, const float* __restrict__ bw,
    float* __restrict__ a_h, float* __restrict__ a_ws) {
    int bg = blockIdx.x;
    int t  = threadIdx.x;

    __shared__ float sw1[1024], swh[1024], sww[1024];
    __shared__ float sy[32][129];     // conv1 output (pad: conflict-free both ways)
    __shared__ float spart[2][4][32];
    __shared__ float sscale[32], sshift[32];

    for (int i = t; i < 1024; i += 128) {
        sw1[i] = w1[i]; swh[i] = wh[i]; sww[i] = ww[i];
    }

    // pooled features for position t, all 32 input channels (coalesced loads)
    float vloc[32];
#pragma unroll
    for (int i = 0; i < 32; ++i) {
        vloc[i] = (t < 64) ? x_h[(size_t)(bg * CG + i) * 64 + t]
                           : x_w[(size_t)(bg * CG + i) * 64 + (t - 64)];
    }
    __syncthreads();

    // conv1: y[o][t] = b1[o] + sum_i w1[o][i]*v[i][t]
    for (int o = 0; o < 32; ++o) {
        float acc = b1[o];
#pragma unroll
        for (int i = 0; i < 32; ++i) acc += sw1[o * 32 + i] * vloc[i];
        sy[o][t] = acc;
    }
    __syncthreads();

    // GN stats per channel o over 128 positions
    {
        int o = t & 31, seg = t >> 5;
        float s = 0.f, ss = 0.f;
#pragma unroll
        for (int p = 0; p < 32; ++p) {
            float v = sy[o][seg * 32 + p];
            s += v; ss += v * v;
        }
        spart[0][seg][o] = s; spart[1][seg][o] = ss;
    }
    __syncthreads();
    if (t < 32) {
        float s  = spart[0][0][t] + spart[0][1][t] + spart[0][2][t] + spart[0][3][t];
        float ss = spart[1][0][t] + spart[1][1][t] + spart[1][2][t] + spart[1][3][t];
        float mu = s * (1.0f / 128.0f);
        float var = ss * (1.0f / 128.0f) - mu * mu;
        float rstd = rsqrtf(var + 1e-5f);
        float sc = rstd * gn_g[t];
        sscale[t] = sc;
        sshift[t] = gn_b[t] - mu * sc;
    }
    __syncthreads();

    // z[i] = h_swish(GN(y))[i][t]
    float z[32];
#pragma unroll
    for (int i = 0; i < 32; ++i) {
        float v = sy[i][t] * sscale[i] + sshift[i];
        float c = fminf(fmaxf(v + 3.0f, 0.0f), 6.0f);
        z[i] = v * c * (1.0f / 6.0f);
    }
    if (t < 64) {
        for (int o = 0; o < 32; ++o) {
            float acc = bh[o];
#pragma unroll
            for (int i = 0; i < 32; ++i) acc += swh[o * 32 + i] * z[i];
            a_h[(size_t)(bg * CG + o) * 64 + t] = acc;
        }
    } else {
        int wc = t - 64;
        for (int o = 0; o < 32; ++o) {
            float acc = bw[o];
#pragma unroll
            for (int i = 0; i < 32; ++i) acc += sww[o * 32 + i] * z[i];
            a_ws[(size_t)(bg * CG + o) * 64 + wc] = acc * x_s[bg * CG + o];
        }
    }
}

// ---------------------------------------------------------------------------
// Kernel 4: spatial gate. One block per x1 plane: 8192 blocks x 256.
// x1 reads should be LLC-hot (freshest read before this, <256 MiB).
// Out stores are non-temporal so they don't evict the x1 we're still reading.
// ---------------------------------------------------------------------------
__global__ __launch_bounds__(256) void k_final(
    const float* __restrict__ x,
    const float* __restrict__ a_h, const float* __restrict__ a_ws,
    float* __restrict__ out) {
    int bid = blockIdx.x;           // 0..8191
    int bg = bid >> 5;              // image 0..255
    int c1 = bid & 31;              // spatial channel 0..31
    int n = bg >> 3, g = bg & 7;
    int cc = g * 64 + 32 + c1;
    int cf = 2 * (cc & 255) + (cc >> 8);
    const f32x4* src = (const f32x4*)(x   + (size_t)(n * 512 + g * 64 + 32 + c1) * HW);
    f32x4*       dst = (f32x4*)      (out + (size_t)(n * 512 + cf) * HW);
    int t = threadIdx.x;

    __shared__ float sah[64], saw[64];
    if (t < 64)       sah[t]      = a_h [(size_t)(bg * CG + c1) * 64 + t];
    else if (t < 128) saw[t - 64] = a_ws[(size_t)(bg * CG + c1) * 64 + (t - 64)];
    __syncthreads();

#pragma unroll
    for (int q = 0; q < 4; ++q) {
        int vi = q * 256 + t;            // float4 index in plane
        f32x4 v = src[vi];
        int h  = vi >> 4;                // 16 float4 per row
        int wb = (vi & 15) * 4;
        float ah = sah[h];
        v[0] *= sigmoidf_(ah * saw[wb + 0]);
        v[1] *= sigmoidf_(ah * saw[wb + 1]);
        v[2] *= sigmoidf_(ah * saw[wb + 2]);
        v[3] *= sigmoidf_(ah * saw[wb + 3]);
        __builtin_nontemporal_store(v, &dst[vi]);
    }
}

// ---------------------------------------------------------------------------
extern "C" void kernel_launch(void* const* d_in, const int* in_sizes, int n_in,
                              void* d_out, int out_size, void* d_ws, size_t ws_size,
                              hipStream_t stream) {
    const float* x        = (const float*)d_in[0];
    const float* cweight  = (const float*)d_in[1];
    const float* cbias    = (const float*)d_in[2];
    const float* conv1_w  = (const float*)d_in[3];
    const float* conv1_b  = (const float*)d_in[4];
    const float* gn_g     = (const float*)d_in[5];
    const float* gn_b     = (const float*)d_in[6];
    const float* convh_w  = (const float*)d_in[7];
    const float* convh_b  = (const float*)d_in[8];
    const float* convw_w  = (const float*)d_in[9];
    const float* convw_b  = (const float*)d_in[10];
    float* out = (float*)d_out;

    // workspace (floats): x_s 8K, x_h/x_w/a_h/a_ws 512K each -> ~8.2 MB
    float* ws   = (float*)d_ws;
    float* x_s  = ws;
    float* x_h  = x_s + NBG * CG;
    float* x_w  = x_h + NBG * CG * 64;
    float* a_h  = x_w + NBG * CG * 64;
    float* a_ws = a_h + NBG * CG * 64;

    k_chan <<<NBG * CG, 256, 0, stream>>>(x, cweight, cbias, out);
    k_pool <<<NBG * CG, 256, 0, stream>>>(x, x_s, x_h, x_w);
    k_mid  <<<NBG, 128, 0, stream>>>(x_h, x_w, x_s,
                                     conv1_w, conv1_b, gn_g, gn_b,
                                     convh_w, convh_b, convw_w, convw_b,
                                     a_h, a_ws);
    k_final<<<NBG * CG, 256, 0, stream>>>(x, a_h, a_ws, out);
}